// Round 4
// baseline (518.026 us; speedup 1.0000x reference)
//
#include <hip/hip_runtime.h>
#include <math.h>

#define TPB 512          // 8 waves/block; 1024 blocks = 4 blocks/CU, 8 waves/SIMD
#define NBLK 1024
#define CCLS 1000

// One row per wave: lane l owns float4 chunks {l, 64+l, 128+l, 192+l} (last valid if l<58).
// Class of chunk k, lane l, comp j: c = k*256 + l*4 + j (0..1023, <1000 valid).
// exp computed IN PLACE over the row-chunk registers to keep live set < 64 VGPRs.
// No max-subtraction: x*inv in [-1,1] after L2 norm -> exp in [0.37, 2.72], softmax shift-invariant.
__global__ __launch_bounds__(TPB, 8) void mdca_main(const float* __restrict__ X,
                                                    float* __restrict__ part, int B) {
  __shared__ float sacc[1024];
  const int t = threadIdx.x;
  const int lane = t & 63;
  const int wid = blockIdx.x * (TPB / 64) + (t >> 6);
  const int nw = NBLK * (TPB / 64);   // 8192 waves
  const bool v3 = (lane < 58);

  for (int i = t; i < 1024; i += TPB) sacc[i] = 0.f;

  float acc[16];
  #pragma unroll
  for (int i = 0; i < 16; ++i) acc[i] = 0.f;

  const float4 Z = make_float4(0.f, 0.f, 0.f, 0.f);

  for (int r0 = wid; r0 < B; r0 += 2 * nw) {
    const int r1 = r0 + nw;
    const bool has1 = (r1 < B);

    const float4* b0 = reinterpret_cast<const float4*>(X + (size_t)r0 * CCLS);
    const float4* b1 = reinterpret_cast<const float4*>(X + (size_t)(has1 ? r1 : r0) * CCLS);

    float4 a0 = b0[lane],       a1 = b0[64 + lane];
    float4 a2 = b0[128 + lane], a3 = v3 ? b0[192 + lane] : Z;
    float4 c0 = b1[lane],       c1 = b1[64 + lane];
    float4 c2 = b1[128 + lane], c3 = v3 ? b1[192 + lane] : Z;

    float ss0 = a0.x*a0.x + a0.y*a0.y + a0.z*a0.z + a0.w*a0.w
              + a1.x*a1.x + a1.y*a1.y + a1.z*a1.z + a1.w*a1.w
              + a2.x*a2.x + a2.y*a2.y + a2.z*a2.z + a2.w*a2.w
              + a3.x*a3.x + a3.y*a3.y + a3.z*a3.z + a3.w*a3.w;
    float ss1 = c0.x*c0.x + c0.y*c0.y + c0.z*c0.z + c0.w*c0.w
              + c1.x*c1.x + c1.y*c1.y + c1.z*c1.z + c1.w*c1.w
              + c2.x*c2.x + c2.y*c2.y + c2.z*c2.z + c2.w*c2.w
              + c3.x*c3.x + c3.y*c3.y + c3.z*c3.z + c3.w*c3.w;

    #pragma unroll
    for (int off = 1; off < 64; off <<= 1) {
      ss0 += __shfl_xor(ss0, off, 64);
      ss1 += __shfl_xor(ss1, off, 64);
    }

    const float inv0 = 1.0f / (sqrtf(ss0) + 1e-7f);
    const float inv1 = 1.0f / (sqrtf(ss1) + 1e-7f);

    // exp in place (overwrite row registers)
    a0.x=__expf(a0.x*inv0); a0.y=__expf(a0.y*inv0); a0.z=__expf(a0.z*inv0); a0.w=__expf(a0.w*inv0);
    a1.x=__expf(a1.x*inv0); a1.y=__expf(a1.y*inv0); a1.z=__expf(a1.z*inv0); a1.w=__expf(a1.w*inv0);
    a2.x=__expf(a2.x*inv0); a2.y=__expf(a2.y*inv0); a2.z=__expf(a2.z*inv0); a2.w=__expf(a2.w*inv0);
    a3.x=__expf(a3.x*inv0); a3.y=__expf(a3.y*inv0); a3.z=__expf(a3.z*inv0); a3.w=__expf(a3.w*inv0);
    c0.x=__expf(c0.x*inv1); c0.y=__expf(c0.y*inv1); c0.z=__expf(c0.z*inv1); c0.w=__expf(c0.w*inv1);
    c1.x=__expf(c1.x*inv1); c1.y=__expf(c1.y*inv1); c1.z=__expf(c1.z*inv1); c1.w=__expf(c1.w*inv1);
    c2.x=__expf(c2.x*inv1); c2.y=__expf(c2.y*inv1); c2.z=__expf(c2.z*inv1); c2.w=__expf(c2.w*inv1);
    c3.x=__expf(c3.x*inv1); c3.y=__expf(c3.y*inv1); c3.z=__expf(c3.z*inv1); c3.w=__expf(c3.w*inv1);
    if (!v3) { a3 = Z; c3 = Z; }   // exp(0)=1 pollution from inactive chunk 3 lanes

    float es0 = a0.x+a0.y+a0.z+a0.w + a1.x+a1.y+a1.z+a1.w
              + a2.x+a2.y+a2.z+a2.w + a3.x+a3.y+a3.z+a3.w;
    float es1 = c0.x+c0.y+c0.z+c0.w + c1.x+c1.y+c1.z+c1.w
              + c2.x+c2.y+c2.z+c2.w + c3.x+c3.y+c3.z+c3.w;
    #pragma unroll
    for (int off = 1; off < 64; off <<= 1) {
      es0 += __shfl_xor(es0, off, 64);
      es1 += __shfl_xor(es1, off, 64);
    }
    const float invS0 = 1.0f / es0;
    const float invS1 = has1 ? (1.0f / es1) : 0.f;

    acc[0]  += a0.x*invS0 + c0.x*invS1;  acc[1]  += a0.y*invS0 + c0.y*invS1;
    acc[2]  += a0.z*invS0 + c0.z*invS1;  acc[3]  += a0.w*invS0 + c0.w*invS1;
    acc[4]  += a1.x*invS0 + c1.x*invS1;  acc[5]  += a1.y*invS0 + c1.y*invS1;
    acc[6]  += a1.z*invS0 + c1.z*invS1;  acc[7]  += a1.w*invS0 + c1.w*invS1;
    acc[8]  += a2.x*invS0 + c2.x*invS1;  acc[9]  += a2.y*invS0 + c2.y*invS1;
    acc[10] += a2.z*invS0 + c2.z*invS1;  acc[11] += a2.w*invS0 + c2.w*invS1;
    acc[12] += a3.x*invS0 + c3.x*invS1;  acc[13] += a3.y*invS0 + c3.y*invS1;
    acc[14] += a3.z*invS0 + c3.z*invS1;  acc[15] += a3.w*invS0 + c3.w*invS1;
  }

  // combine 8 waves in LDS (sacc index == class), then ONE float4 store per thread (no global atomics)
  __syncthreads();
  #pragma unroll
  for (int k = 0; k < 4; ++k)
    #pragma unroll
    for (int j = 0; j < 4; ++j)
      atomicAdd(&sacc[k * 256 + lane * 4 + j], acc[k * 4 + j]);
  __syncthreads();
  if (t < 256) {
    float4 v = *reinterpret_cast<float4*>(&sacc[t * 4]);
    *reinterpret_cast<float4*>(&part[(size_t)blockIdx.x * 1024 + t * 4]) = v;
  }
}

// ---------------- bincount via LDS histogram ----------------
__global__ __launch_bounds__(256) void mdca_count(const int* __restrict__ tgt,
                                                  float* __restrict__ g_cnt, int B) {
  __shared__ int scnt[CCLS];
  for (int i = threadIdx.x; i < CCLS; i += 256) scnt[i] = 0;
  __syncthreads();
  for (int i = blockIdx.x * 256 + threadIdx.x; i < B; i += gridDim.x * 256)
    atomicAdd(&scnt[tgt[i]], 1);
  __syncthreads();
  for (int i = threadIdx.x; i < CCLS; i += 256) {
    int v = scnt[i];
    if (v) atomicAdd(&g_cnt[i], (float)v);
  }
}

// ---------------- reduce partials + epilogue: mean |avg_conf - avg_count| ----------------
__global__ __launch_bounds__(64) void mdca_final(const float* __restrict__ part,
                                                 const float* __restrict__ g_cnt,
                                                 float* __restrict__ out, int B) {
  const int c = blockIdx.x * 64 + threadIdx.x;
  float s = 0.f;
  if (c < CCLS) {
    float p0 = 0.f, p1 = 0.f, p2 = 0.f, p3 = 0.f;
    for (int b = 0; b < NBLK; b += 4) {
      p0 += part[(size_t)(b    ) * 1024 + c];
      p1 += part[(size_t)(b + 1) * 1024 + c];
      p2 += part[(size_t)(b + 2) * 1024 + c];
      p3 += part[(size_t)(b + 3) * 1024 + c];
    }
    s = fabsf((p0 + p1 + p2 + p3) - g_cnt[c]);
  }
  #pragma unroll
  for (int off = 1; off < 64; off <<= 1) s += __shfl_xor(s, off, 64);
  if (threadIdx.x == 0)
    atomicAdd(out, s / ((float)B * (float)CCLS));
}

extern "C" void kernel_launch(void* const* d_in, const int* in_sizes, int n_in,
                              void* d_out, int out_size, void* d_ws, size_t ws_size,
                              hipStream_t stream) {
  const float* X = (const float*)d_in[0];
  const int* tgt = (const int*)d_in[1];
  const int B = in_sizes[1];

  float* g_cnt = (float*)d_ws;                      // [1024]
  float* part  = (float*)((char*)d_ws + 16384);     // [NBLK * 1024] = 4 MB

  hipMemsetAsync(g_cnt, 0, 1024 * sizeof(float), stream);
  hipMemsetAsync(d_out, 0, out_size * sizeof(float), stream);

  mdca_count<<<32, 256, 0, stream>>>(tgt, g_cnt, B);
  mdca_main<<<NBLK, TPB, 0, stream>>>(X, part, B);
  mdca_final<<<(CCLS + 63) / 64, 64, 0, stream>>>(part, g_cnt, (float*)d_out, B);
}

// Round 5
// 420.968 us; speedup vs baseline: 1.2306x; 1.2306x over previous
//
#include <hip/hip_runtime.h>
#include <math.h>

#define TPB 256          // 4 waves/block
#define NBLK 1024        // 4 blocks/CU -> 16 waves/CU
#define CCLS 1000

// One row per wave: lane l owns float4 chunks {l, 64+l, 128+l, 192+l} (last valid if l<58).
// Class of chunk k, lane l, comp j: c = k*256 + l*4 + j (0..1023, <1000 valid).
// Software-pipelined: next row-pair's loads are issued BEFORE the current pair's
// reduction chain so memory stays in flight during the shfl/exp dependency chain.
// No max-subtraction: x*inv in [-1,1] after L2 norm -> exp in [0.37,2.72], softmax shift-invariant.

#define LOADP(R, x0, x1, x2, x3, y0, y1, y2, y3)                                   \
  {                                                                                \
    const int _r1 = (R) + nw;                                                      \
    const float4* _b0 = reinterpret_cast<const float4*>(X + (size_t)(R) * CCLS);   \
    const float4* _b1 =                                                            \
        reinterpret_cast<const float4*>(X + (size_t)(_r1 < B ? _r1 : (R)) * CCLS); \
    x0 = _b0[lane];      x1 = _b0[64 + lane];                                      \
    x2 = _b0[128 + lane]; x3 = v3 ? _b0[192 + lane] : Z;                           \
    y0 = _b1[lane];      y1 = _b1[64 + lane];                                      \
    y2 = _b1[128 + lane]; y3 = v3 ? _b1[192 + lane] : Z;                           \
  }

__global__ __launch_bounds__(TPB, 4) void mdca_main(const float* __restrict__ X,
                                                    float* __restrict__ g_acc, int B) {
  __shared__ float sacc[1024];
  const int t = threadIdx.x;
  const int lane = t & 63;
  const int wid = blockIdx.x * (TPB / 64) + (t >> 6);
  const int nw = NBLK * (TPB / 64);   // 4096 waves -> 16 rows/wave (8 pairs)
  const bool v3 = (lane < 58);

  for (int i = t; i < 1024; i += TPB) sacc[i] = 0.f;

  float acc[16];
  #pragma unroll
  for (int i = 0; i < 16; ++i) acc[i] = 0.f;

  const float4 Z = make_float4(0.f, 0.f, 0.f, 0.f);

  float4 a0, a1, a2, a3, c0, c1, c2, c3;
  int r0 = wid;
  if (r0 < B) LOADP(r0, a0, a1, a2, a3, c0, c1, c2, c3);

  while (r0 < B) {
    const int rn = r0 + 2 * nw;
    float4 na0 = Z, na1 = Z, na2 = Z, na3 = Z, nc0 = Z, nc1 = Z, nc2 = Z, nc3 = Z;
    if (rn < B) LOADP(rn, na0, na1, na2, na3, nc0, nc1, nc2, nc3);   // prefetch in flight

    const bool has1 = (r0 + nw) < B;

    float ss0 = a0.x*a0.x + a0.y*a0.y + a0.z*a0.z + a0.w*a0.w
              + a1.x*a1.x + a1.y*a1.y + a1.z*a1.z + a1.w*a1.w
              + a2.x*a2.x + a2.y*a2.y + a2.z*a2.z + a2.w*a2.w
              + a3.x*a3.x + a3.y*a3.y + a3.z*a3.z + a3.w*a3.w;
    float ss1 = c0.x*c0.x + c0.y*c0.y + c0.z*c0.z + c0.w*c0.w
              + c1.x*c1.x + c1.y*c1.y + c1.z*c1.z + c1.w*c1.w
              + c2.x*c2.x + c2.y*c2.y + c2.z*c2.z + c2.w*c2.w
              + c3.x*c3.x + c3.y*c3.y + c3.z*c3.z + c3.w*c3.w;

    #pragma unroll
    for (int off = 1; off < 64; off <<= 1) {
      ss0 += __shfl_xor(ss0, off, 64);
      ss1 += __shfl_xor(ss1, off, 64);
    }

    const float inv0 = 1.0f / (sqrtf(ss0) + 1e-7f);
    const float inv1 = 1.0f / (sqrtf(ss1) + 1e-7f);

    // exp in place (overwrite row registers)
    a0.x=__expf(a0.x*inv0); a0.y=__expf(a0.y*inv0); a0.z=__expf(a0.z*inv0); a0.w=__expf(a0.w*inv0);
    a1.x=__expf(a1.x*inv0); a1.y=__expf(a1.y*inv0); a1.z=__expf(a1.z*inv0); a1.w=__expf(a1.w*inv0);
    a2.x=__expf(a2.x*inv0); a2.y=__expf(a2.y*inv0); a2.z=__expf(a2.z*inv0); a2.w=__expf(a2.w*inv0);
    a3.x=__expf(a3.x*inv0); a3.y=__expf(a3.y*inv0); a3.z=__expf(a3.z*inv0); a3.w=__expf(a3.w*inv0);
    c0.x=__expf(c0.x*inv1); c0.y=__expf(c0.y*inv1); c0.z=__expf(c0.z*inv1); c0.w=__expf(c0.w*inv1);
    c1.x=__expf(c1.x*inv1); c1.y=__expf(c1.y*inv1); c1.z=__expf(c1.z*inv1); c1.w=__expf(c1.w*inv1);
    c2.x=__expf(c2.x*inv1); c2.y=__expf(c2.y*inv1); c2.z=__expf(c2.z*inv1); c2.w=__expf(c2.w*inv1);
    c3.x=__expf(c3.x*inv1); c3.y=__expf(c3.y*inv1); c3.z=__expf(c3.z*inv1); c3.w=__expf(c3.w*inv1);
    if (!v3) { a3 = Z; c3 = Z; }   // kill exp(0)=1 pollution from inactive chunk-3 lanes

    float es0 = a0.x+a0.y+a0.z+a0.w + a1.x+a1.y+a1.z+a1.w
              + a2.x+a2.y+a2.z+a2.w + a3.x+a3.y+a3.z+a3.w;
    float es1 = c0.x+c0.y+c0.z+c0.w + c1.x+c1.y+c1.z+c1.w
              + c2.x+c2.y+c2.z+c2.w + c3.x+c3.y+c3.z+c3.w;
    #pragma unroll
    for (int off = 1; off < 64; off <<= 1) {
      es0 += __shfl_xor(es0, off, 64);
      es1 += __shfl_xor(es1, off, 64);
    }
    const float invS0 = 1.0f / es0;
    const float invS1 = has1 ? (1.0f / es1) : 0.f;

    acc[0]  += a0.x*invS0 + c0.x*invS1;  acc[1]  += a0.y*invS0 + c0.y*invS1;
    acc[2]  += a0.z*invS0 + c0.z*invS1;  acc[3]  += a0.w*invS0 + c0.w*invS1;
    acc[4]  += a1.x*invS0 + c1.x*invS1;  acc[5]  += a1.y*invS0 + c1.y*invS1;
    acc[6]  += a1.z*invS0 + c1.z*invS1;  acc[7]  += a1.w*invS0 + c1.w*invS1;
    acc[8]  += a2.x*invS0 + c2.x*invS1;  acc[9]  += a2.y*invS0 + c2.y*invS1;
    acc[10] += a2.z*invS0 + c2.z*invS1;  acc[11] += a2.w*invS0 + c2.w*invS1;
    acc[12] += a3.x*invS0 + c3.x*invS1;  acc[13] += a3.y*invS0 + c3.y*invS1;
    acc[14] += a3.z*invS0 + c3.z*invS1;  acc[15] += a3.w*invS0 + c3.w*invS1;

    // rotate pipeline
    a0 = na0; a1 = na1; a2 = na2; a3 = na3;
    c0 = nc0; c1 = nc1; c2 = nc2; c3 = nc3;
    r0 = rn;
  }

  // combine 4 waves in LDS (sacc index == class), then one global atomic per class per block
  __syncthreads();
  #pragma unroll
  for (int k = 0; k < 4; ++k)
    #pragma unroll
    for (int j = 0; j < 4; ++j)
      atomicAdd(&sacc[k * 256 + lane * 4 + j], acc[k * 4 + j]);
  __syncthreads();
  #pragma unroll
  for (int j = 0; j < 4; ++j) {
    int c = t * 4 + j;
    if (c < CCLS) atomicAdd(&g_acc[c], sacc[c]);
  }
}

// ---------------- bincount via LDS histogram ----------------
__global__ __launch_bounds__(256) void mdca_count(const int* __restrict__ tgt,
                                                  float* __restrict__ g_cnt, int B) {
  __shared__ int scnt[CCLS];
  for (int i = threadIdx.x; i < CCLS; i += 256) scnt[i] = 0;
  __syncthreads();
  for (int i = blockIdx.x * 256 + threadIdx.x; i < B; i += gridDim.x * 256)
    atomicAdd(&scnt[tgt[i]], 1);
  __syncthreads();
  for (int i = threadIdx.x; i < CCLS; i += 256) {
    int v = scnt[i];
    if (v) atomicAdd(&g_cnt[i], (float)v);
  }
}

// ---------------- epilogue: mean |avg_conf - avg_count| ----------------
__global__ __launch_bounds__(256) void mdca_final(const float* __restrict__ g_acc,
                                                  const float* __restrict__ g_cnt,
                                                  float* __restrict__ out, int B) {
  __shared__ float s_r[4];
  int t = threadIdx.x;
  float invB = 1.0f / (float)B;
  float s = 0.f;
  for (int c = t; c < CCLS; c += 256)
    s += fabsf((g_acc[c] - g_cnt[c]) * invB);
  #pragma unroll
  for (int off = 32; off > 0; off >>= 1) s += __shfl_down(s, off, 64);
  if ((t & 63) == 0) s_r[t >> 6] = s;
  __syncthreads();
  if (t == 0) out[0] = (s_r[0] + s_r[1] + s_r[2] + s_r[3]) / (float)CCLS;
}

extern "C" void kernel_launch(void* const* d_in, const int* in_sizes, int n_in,
                              void* d_out, int out_size, void* d_ws, size_t ws_size,
                              hipStream_t stream) {
  const float* X = (const float*)d_in[0];
  const int* tgt = (const int*)d_in[1];
  const int B = in_sizes[1];

  float* g_acc = (float*)d_ws;   // [1024] (first 1000 used)
  float* g_cnt = g_acc + 1024;   // [1024]

  hipMemsetAsync(d_ws, 0, 2048 * sizeof(float), stream);

  mdca_count<<<32, 256, 0, stream>>>(tgt, g_cnt, B);
  mdca_main<<<NBLK, TPB, 0, stream>>>(X, g_acc, B);
  mdca_final<<<1, 256, 0, stream>>>(g_acc, g_cnt, (float*)d_out, B);
}

// Round 6
// 381.752 us; speedup vs baseline: 1.3570x; 1.1027x over previous
//
#include <hip/hip_runtime.h>
#include <math.h>

#define TPB 512          // 8 waves/block; 1024 blocks -> 8 waves/SIMD (full occupancy)
#define NBLK 1024
#define CCLS 1000

// Wave-wide f32 sum via DPP (VALU pipe only, no DS/lgkmcnt):
// row_shr 1/2/4/8 -> lane15 of each 16-row holds row sum;
// row_bcast:15 (rows 1,3) and row_bcast:31 (rows 2,3) combine -> lane 63 = total.
// readlane(63) broadcasts through an SGPR. Chain = 6 VALU adds + 1 readlane.
__device__ __forceinline__ float wave_sum64(float x) {
  int t;
  t = __builtin_amdgcn_update_dpp(0, __float_as_int(x), 0x111, 0xf, 0xf, true); x += __int_as_float(t); // row_shr:1
  t = __builtin_amdgcn_update_dpp(0, __float_as_int(x), 0x112, 0xf, 0xf, true); x += __int_as_float(t); // row_shr:2
  t = __builtin_amdgcn_update_dpp(0, __float_as_int(x), 0x114, 0xf, 0xf, true); x += __int_as_float(t); // row_shr:4
  t = __builtin_amdgcn_update_dpp(0, __float_as_int(x), 0x118, 0xf, 0xf, true); x += __int_as_float(t); // row_shr:8
  t = __builtin_amdgcn_update_dpp(0, __float_as_int(x), 0x142, 0xa, 0xf, true); x += __int_as_float(t); // row_bcast:15 -> rows 1,3
  t = __builtin_amdgcn_update_dpp(0, __float_as_int(x), 0x143, 0xc, 0xf, true); x += __int_as_float(t); // row_bcast:31 -> rows 2,3
  return __int_as_float(__builtin_amdgcn_readlane(__float_as_int(x), 63));
}

// One row per wave per iteration: lane l owns float4 chunks {l, 64+l, 128+l, 192+l}
// (last valid if l<58). Class of chunk k, lane l, comp j: c = k*256 + l*4 + j.
// No max-subtraction: x*inv in [-1,1] after L2 norm -> exp in [0.37,2.72],
// softmax shift-invariant.
__global__ __launch_bounds__(TPB, 8) void mdca_main(const float* __restrict__ X,
                                                    float* __restrict__ g_acc, int B) {
  __shared__ float sacc[1024];
  const int t = threadIdx.x;
  const int lane = t & 63;
  const int wid = blockIdx.x * (TPB / 64) + (t >> 6);
  const int nw = NBLK * (TPB / 64);   // 8192 waves -> 8 rows/wave
  const bool v3 = (lane < 58);

  for (int i = t; i < 1024; i += TPB) sacc[i] = 0.f;

  float acc[16];
  #pragma unroll
  for (int i = 0; i < 16; ++i) acc[i] = 0.f;

  const float4 Z = make_float4(0.f, 0.f, 0.f, 0.f);

  for (int r = wid; r < B; r += nw) {
    const float4* b = reinterpret_cast<const float4*>(X + (size_t)r * CCLS);
    float4 a0 = b[lane];
    float4 a1 = b[64 + lane];
    float4 a2 = b[128 + lane];
    float4 a3 = v3 ? b[192 + lane] : Z;

    float ss = a0.x*a0.x + a0.y*a0.y + a0.z*a0.z + a0.w*a0.w
             + a1.x*a1.x + a1.y*a1.y + a1.z*a1.z + a1.w*a1.w
             + a2.x*a2.x + a2.y*a2.y + a2.z*a2.z + a2.w*a2.w
             + a3.x*a3.x + a3.y*a3.y + a3.z*a3.z + a3.w*a3.w;
    ss = wave_sum64(ss);

    const float inv = 1.0f / (sqrtf(ss) + 1e-7f);

    // exp in place
    a0.x=__expf(a0.x*inv); a0.y=__expf(a0.y*inv); a0.z=__expf(a0.z*inv); a0.w=__expf(a0.w*inv);
    a1.x=__expf(a1.x*inv); a1.y=__expf(a1.y*inv); a1.z=__expf(a1.z*inv); a1.w=__expf(a1.w*inv);
    a2.x=__expf(a2.x*inv); a2.y=__expf(a2.y*inv); a2.z=__expf(a2.z*inv); a2.w=__expf(a2.w*inv);
    a3.x=__expf(a3.x*inv); a3.y=__expf(a3.y*inv); a3.z=__expf(a3.z*inv); a3.w=__expf(a3.w*inv);
    if (!v3) a3 = Z;   // kill exp(0)=1 pollution from inactive chunk-3 lanes

    float es = a0.x+a0.y+a0.z+a0.w + a1.x+a1.y+a1.z+a1.w
             + a2.x+a2.y+a2.z+a2.w + a3.x+a3.y+a3.z+a3.w;
    es = wave_sum64(es);

    const float invS = 1.0f / es;

    acc[0]  += a0.x*invS;  acc[1]  += a0.y*invS;  acc[2]  += a0.z*invS;  acc[3]  += a0.w*invS;
    acc[4]  += a1.x*invS;  acc[5]  += a1.y*invS;  acc[6]  += a1.z*invS;  acc[7]  += a1.w*invS;
    acc[8]  += a2.x*invS;  acc[9]  += a2.y*invS;  acc[10] += a2.z*invS;  acc[11] += a2.w*invS;
    acc[12] += a3.x*invS;  acc[13] += a3.y*invS;  acc[14] += a3.z*invS;  acc[15] += a3.w*invS;
  }

  // combine 8 waves in LDS (sacc index == class), then one global atomic per class per block
  __syncthreads();
  #pragma unroll
  for (int k = 0; k < 4; ++k)
    #pragma unroll
    for (int j = 0; j < 4; ++j)
      atomicAdd(&sacc[k * 256 + lane * 4 + j], acc[k * 4 + j]);
  __syncthreads();
  #pragma unroll
  for (int j = 0; j < 2; ++j) {
    int c = t * 2 + j;
    if (c < CCLS) atomicAdd(&g_acc[c], sacc[c]);
  }
}

// ---------------- bincount via LDS histogram ----------------
__global__ __launch_bounds__(256) void mdca_count(const int* __restrict__ tgt,
                                                  float* __restrict__ g_cnt, int B) {
  __shared__ int scnt[CCLS];
  for (int i = threadIdx.x; i < CCLS; i += 256) scnt[i] = 0;
  __syncthreads();
  for (int i = blockIdx.x * 256 + threadIdx.x; i < B; i += gridDim.x * 256)
    atomicAdd(&scnt[tgt[i]], 1);
  __syncthreads();
  for (int i = threadIdx.x; i < CCLS; i += 256) {
    int v = scnt[i];
    if (v) atomicAdd(&g_cnt[i], (float)v);
  }
}

// ---------------- epilogue: mean |avg_conf - avg_count| ----------------
__global__ __launch_bounds__(256) void mdca_final(const float* __restrict__ g_acc,
                                                  const float* __restrict__ g_cnt,
                                                  float* __restrict__ out, int B) {
  __shared__ float s_r[4];
  int t = threadIdx.x;
  float invB = 1.0f / (float)B;
  float s = 0.f;
  for (int c = t; c < CCLS; c += 256)
    s += fabsf((g_acc[c] - g_cnt[c]) * invB);
  #pragma unroll
  for (int off = 32; off > 0; off >>= 1) s += __shfl_down(s, off, 64);
  if ((t & 63) == 0) s_r[t >> 6] = s;
  __syncthreads();
  if (t == 0) out[0] = (s_r[0] + s_r[1] + s_r[2] + s_r[3]) / (float)CCLS;
}

extern "C" void kernel_launch(void* const* d_in, const int* in_sizes, int n_in,
                              void* d_out, int out_size, void* d_ws, size_t ws_size,
                              hipStream_t stream) {
  const float* X = (const float*)d_in[0];
  const int* tgt = (const int*)d_in[1];
  const int B = in_sizes[1];

  float* g_acc = (float*)d_ws;   // [1024] (first 1000 used)
  float* g_cnt = g_acc + 1024;   // [1024]

  hipMemsetAsync(d_ws, 0, 2048 * sizeof(float), stream);

  mdca_count<<<32, 256, 0, stream>>>(tgt, g_cnt, B);
  mdca_main<<<NBLK, TPB, 0, stream>>>(X, g_acc, B);
  mdca_final<<<1, 256, 0, stream>>>(g_acc, g_cnt, (float*)d_out, B);
}